// Round 2
// baseline (147.381 us; speedup 1.0000x reference)
//
#include <hip/hip_runtime.h>

#define DIM 256
#define GRP 16
#define LEV0 9   // levels LEV0..LEV0+NLEV-1 use the grouped kernel (N=16383 tree)
#define NLEV 4

#define FMA4(a, sc, v) \
    a.x = fmaf((sc), (v).x, a.x); a.y = fmaf((sc), (v).y, a.y); \
    a.z = fmaf((sc), (v).z, a.z); a.w = fmaf((sc), (v).w, a.w);

// ---------------- sort: bucket levels 9..12 nodes by symbol ----------------
// order[] laid out per level with capacity n_d + 240, buckets padded to x16,
// unused slots = -1. Single block, trivial cost.
__global__ __launch_bounds__(1024) void sort_kernel(const int* __restrict__ x_sym,
                                                    int* __restrict__ order) {
    __shared__ int cnt_s[NLEV * 16];
    __shared__ int cur_s[NLEV * 16];
    const int t = threadIdx.x;
    const int CAP = ((1 << (LEV0 + NLEV)) - (1 << LEV0)) + NLEV * 240;  // 8640
    for (int i = t; i < CAP; i += 1024) order[i] = -1;
    if (t < NLEV * 16) cnt_s[t] = 0;
    __syncthreads();
    const int lo = (1 << LEV0) - 1, hi = (1 << (LEV0 + NLEV)) - 1;  // 511..8190
    for (int i = lo + t; i < hi; i += 1024) {
        const int li = (31 - __clz(i + 1)) - LEV0;
        atomicAdd(&cnt_s[li * 16 + x_sym[i]], 1);
    }
    __syncthreads();
    if (t < NLEV) {
        int run = 0;
        for (int k = 0; k < t; ++k) run += (1 << (LEV0 + k)) + 240;
        for (int s2 = 0; s2 < 16; ++s2) {
            cur_s[t * 16 + s2] = run;
            run += ((cnt_s[t * 16 + s2] + GRP - 1) / GRP) * GRP;
        }
    }
    __syncthreads();
    for (int i = lo + t; i < hi; i += 1024) {
        const int li = (31 - __clz(i + 1)) - LEV0;
        const int pos = atomicAdd(&cur_s[li * 16 + x_sym[i]], 1);
        order[pos] = i;
    }
}

// -------- grouped level: 16 same-symbol nodes / block, W streamed once --------
// 256 threads = 4 waves; wave w owns nodes 4w..4w+3; lane owns 4 columns.
__global__ __launch_bounds__(256) void level_grouped(const int* __restrict__ x_sym,
                                                     const float* __restrict__ W,
                                                     const float* __restrict__ b,
                                                     float* __restrict__ enc,
                                                     const int* __restrict__ order,
                                                     int level_off, int leaf_children) {
    __shared__ float mean_s[GRP][DIM];  // 16 KB
    const int base = level_off + blockIdx.x * GRP;
    const int n0 = order[base];
    if (n0 < 0) return;                 // block-uniform: trailing padding region
    const int s = x_sym[n0];
    const int w = threadIdx.x >> 6;
    const int c = (threadIdx.x & 63) << 2;

    int mynode[4];
    #pragma unroll
    for (int j = 0; j < 4; ++j) {
        const int node = order[base + w * 4 + j];
        mynode[j] = node;
        float4 m = make_float4(0.f, 0.f, 0.f, 0.f);
        if (node >= 0) {
            const int c0 = 2 * node + 1;
            if (leaf_children) {  // children are leaves: enc_child = tanh(b[sym])
                const int sa = x_sym[c0], sb = x_sym[c0 + 1];
                const float4 ba = *(const float4*)(b + sa * DIM + c);
                const float4 bb = *(const float4*)(b + sb * DIM + c);
                m.x = 0.5f * (tanhf(ba.x) + tanhf(bb.x));
                m.y = 0.5f * (tanhf(ba.y) + tanhf(bb.y));
                m.z = 0.5f * (tanhf(ba.z) + tanhf(bb.z));
                m.w = 0.5f * (tanhf(ba.w) + tanhf(bb.w));
            } else {
                const float4 ea = *(const float4*)(enc + (size_t)c0 * DIM + c);
                const float4 eb = *(const float4*)(enc + (size_t)(c0 + 1) * DIM + c);
                m.x = 0.5f * (ea.x + eb.x);
                m.y = 0.5f * (ea.y + eb.y);
                m.z = 0.5f * (ea.z + eb.z);
                m.w = 0.5f * (ea.w + eb.w);
            }
        }
        *(float4*)(&mean_s[w * 4 + j][c]) = m;
    }
    __syncthreads();

    float4 acc0 = make_float4(0, 0, 0, 0), acc1 = acc0, acc2 = acc0, acc3 = acc0;
    const float* __restrict__ Ws = W + ((size_t)s << 16);
    // 4 outer segments keep waves loosely in step -> L1 multicast on shared W.
    for (int seg = 0; seg < 4; ++seg) {
        const int d0 = seg * 64;
        #pragma unroll 2
        for (int d = d0; d < d0 + 64; d += 4) {
            const float4 w0 = *(const float4*)(Ws + (size_t)(d + 0) * DIM + c);
            const float4 w1 = *(const float4*)(Ws + (size_t)(d + 1) * DIM + c);
            const float4 w2 = *(const float4*)(Ws + (size_t)(d + 2) * DIM + c);
            const float4 w3 = *(const float4*)(Ws + (size_t)(d + 3) * DIM + c);
            const float4 m0 = *(const float4*)(&mean_s[w * 4 + 0][d]);
            const float4 m1 = *(const float4*)(&mean_s[w * 4 + 1][d]);
            const float4 m2 = *(const float4*)(&mean_s[w * 4 + 2][d]);
            const float4 m3 = *(const float4*)(&mean_s[w * 4 + 3][d]);
            FMA4(acc0, m0.x, w0); FMA4(acc0, m0.y, w1); FMA4(acc0, m0.z, w2); FMA4(acc0, m0.w, w3);
            FMA4(acc1, m1.x, w0); FMA4(acc1, m1.y, w1); FMA4(acc1, m1.z, w2); FMA4(acc1, m1.w, w3);
            FMA4(acc2, m2.x, w0); FMA4(acc2, m2.y, w1); FMA4(acc2, m2.z, w2); FMA4(acc2, m2.w, w3);
            FMA4(acc3, m3.x, w0); FMA4(acc3, m3.y, w1); FMA4(acc3, m3.z, w2); FMA4(acc3, m3.w, w3);
        }
        __syncthreads();
    }

    const float4 bs = *(const float4*)(b + s * DIM + c);
    float4 accs[4] = {acc0, acc1, acc2, acc3};
    #pragma unroll
    for (int j = 0; j < 4; ++j) {
        const int node = mynode[j];
        if (node < 0) continue;
        float4 r;
        r.x = tanhf(accs[j].x + bs.x);
        r.y = tanhf(accs[j].y + bs.y);
        r.z = tanhf(accs[j].z + bs.z);
        r.w = tanhf(accs[j].w + bs.w);
        *(float4*)(enc + (size_t)node * DIM + c) = r;
    }
}

// -------- small levels (n <= 256): 4 blocks/node, 64-col tile + 4-way K split --------
__global__ __launch_bounds__(256) void level_small(const int* __restrict__ x_sym,
                                                   const float* __restrict__ W,
                                                   const float* __restrict__ b,
                                                   float* __restrict__ enc,
                                                   int lo, int N) {
    const int node = lo + (blockIdx.x >> 2);
    const int tile = blockIdx.x & 3;
    const int t = threadIdx.x;
    const int kc = t >> 6;
    const int lane = t & 63;
    const int c = tile * 64 + lane;

    __shared__ float mean_s[DIM];
    __shared__ float part[256];

    const int s = x_sym[node];
    const int c0 = 2 * node + 1;

    float m = 0.0f;
    if (c0 < N)
        m = 0.5f * (enc[(size_t)c0 * DIM + t] + enc[(size_t)(c0 + 1) * DIM + t]);
    mean_s[t] = m;
    __syncthreads();

    float acc = 0.0f;
    if (c0 < N) {
        const float* __restrict__ Ws = W + ((size_t)s << 16);
        const int d0 = kc * 64;
        #pragma unroll 8
        for (int d = d0; d < d0 + 64; ++d)
            acc = fmaf(mean_s[d], Ws[d * DIM + c], acc);
    }
    part[t] = acc;
    __syncthreads();

    if (t < 64) {
        float r = part[t] + part[t + 64] + part[t + 128] + part[t + 192];
        r += b[s * DIM + c];
        enc[(size_t)node * DIM + c] = tanhf(r);
    }
}

// legacy fallback (generic shapes)
__global__ __launch_bounds__(256) void level_big(const int* __restrict__ x_sym,
                                                 const float* __restrict__ W,
                                                 const float* __restrict__ b,
                                                 float* __restrict__ enc,
                                                 int lo, int N) {
    const int node = lo + blockIdx.x;
    const int e = threadIdx.x;
    __shared__ float mean_s[DIM];
    const int s = x_sym[node];
    const int c0 = 2 * node + 1;

    float acc = b[s * DIM + e];
    if (c0 < N) {
        mean_s[e] = 0.5f * (enc[(size_t)c0 * DIM + e] + enc[(size_t)(c0 + 1) * DIM + e]);
        __syncthreads();
        const float* __restrict__ Ws = W + ((size_t)s << 16);
        #pragma unroll 8
        for (int d = 0; d < DIM; ++d)
            acc = fmaf(mean_s[d], Ws[d * DIM + e], acc);
    }
    enc[(size_t)node * DIM + e] = tanhf(acc);
}

// -------- head: out = enc[root] @ W_out + b_out (OUT=10) --------
__global__ __launch_bounds__(256) void out_kernel10(const float* __restrict__ enc,
                                                    const float* __restrict__ W_out,
                                                    const float* __restrict__ b_out,
                                                    float* __restrict__ out) {
    const int t = threadIdx.x;
    const float e = enc[t];
    float p[10];
    #pragma unroll
    for (int o = 0; o < 10; ++o) p[o] = e * W_out[t * 10 + o];
    #pragma unroll
    for (int o = 0; o < 10; ++o)
        #pragma unroll
        for (int k = 32; k >= 1; k >>= 1) p[o] += __shfl_xor(p[o], k, 64);
    __shared__ float part[4][10];
    if ((t & 63) == 0) {
        #pragma unroll
        for (int o = 0; o < 10; ++o) part[t >> 6][o] = p[o];
    }
    __syncthreads();
    if (t < 10) out[t] = b_out[t] + part[0][t] + part[1][t] + part[2][t] + part[3][t];
}

__global__ void out_kernel(const float* __restrict__ enc,
                           const float* __restrict__ W_out,
                           const float* __restrict__ b_out,
                           float* __restrict__ out, int outn) {
    const int o = threadIdx.x;
    if (o < outn) {
        float acc = b_out[o];
        for (int d = 0; d < DIM; ++d)
            acc = fmaf(enc[d], W_out[d * outn + o], acc);
        out[o] = acc;
    }
}

extern "C" void kernel_launch(void* const* d_in, const int* in_sizes, int n_in,
                              void* d_out, int out_size, void* d_ws, size_t ws_size,
                              hipStream_t stream) {
    const int*   x_sym = (const int*)d_in[0];
    const float* W     = (const float*)d_in[2];
    const float* b     = (const float*)d_in[3];
    const float* W_out = (const float*)d_in[4];
    const float* b_out = (const float*)d_in[5];
    float* out = (float*)d_out;
    float* enc = (float*)d_ws;                      // N x 256 fp32
    const int N = in_sizes[0];

    int depth = 0;
    while (((1 << depth) - 1) < N) ++depth;

    if (N == (1 << 14) - 1 && out_size == 10) {
        int* order = (int*)(enc + (size_t)N * DIM);  // 8640 ints
        sort_kernel<<<1, 1024, 0, stream>>>(x_sym, order);
        // grouped deep levels, leaves folded into d = depth-2
        for (int d = LEV0 + NLEV - 1; d >= LEV0; --d) {
            const int li = d - LEV0;
            int off = 0;
            for (int k = 0; k < li; ++k) off += (1 << (LEV0 + k)) + 240;
            const int blocks = (1 << d) / GRP + 15;
            level_grouped<<<blocks, 256, 0, stream>>>(x_sym, W, b, enc, order, off,
                                                      (d == depth - 2) ? 1 : 0);
        }
        // small levels d = 8..0
        for (int d = LEV0 - 1; d >= 0; --d) {
            const int lo = (1 << d) - 1;
            const int n = (1 << d);
            level_small<<<n * 4, 256, 0, stream>>>(x_sym, W, b, enc, lo, N);
        }
        out_kernel10<<<1, 256, 0, stream>>>(enc, W_out, b_out, out);
    } else {
        for (int d = depth - 1; d >= 0; --d) {
            int lo = (1 << d) - 1;
            int n = (1 << d);
            if (lo + n > N) n = N - lo;
            if (n >= 256)
                level_big<<<n, 256, 0, stream>>>(x_sym, W, b, enc, lo, N);
            else
                level_small<<<n * 4, 256, 0, stream>>>(x_sym, W, b, enc, lo, N);
        }
        out_kernel<<<1, 64, 0, stream>>>(enc, W_out, b_out, out, out_size);
    }
}

// Round 3
// 92.347 us; speedup vs baseline: 1.5960x; 1.5960x over previous
//
#include <hip/hip_runtime.h>

#define DIM 256
#define GRP 16
#define LEV0 9   // levels LEV0..LEV0+NLEV-1 use the grouped kernel (N=16383 tree)
#define NLEV 4
#define MPAD 260 // mean_s row stride (floats); +4 pad -> 2-way bank aliasing (free)

#define FMA4(a, sc, v) \
    a.x = fmaf((sc), (v).x, a.x); a.y = fmaf((sc), (v).y, a.y); \
    a.z = fmaf((sc), (v).z, a.z); a.w = fmaf((sc), (v).w, a.w);

// ---------------- sort: bucket levels 9..12 nodes by symbol ----------------
__global__ __launch_bounds__(1024) void sort_kernel(const int* __restrict__ x_sym,
                                                    int* __restrict__ order) {
    __shared__ int cnt_s[NLEV * 16];
    __shared__ int cur_s[NLEV * 16];
    const int t = threadIdx.x;
    const int CAP = ((1 << (LEV0 + NLEV)) - (1 << LEV0)) + NLEV * 240;  // 8640
    for (int i = t; i < CAP; i += 1024) order[i] = -1;
    if (t < NLEV * 16) cnt_s[t] = 0;
    __syncthreads();
    const int lo = (1 << LEV0) - 1, hi = (1 << (LEV0 + NLEV)) - 1;  // 511..8190
    for (int i = lo + t; i < hi; i += 1024) {
        const int li = (31 - __clz(i + 1)) - LEV0;
        atomicAdd(&cnt_s[li * 16 + x_sym[i]], 1);
    }
    __syncthreads();
    if (t < NLEV) {
        int run = 0;
        for (int k = 0; k < t; ++k) run += (1 << (LEV0 + k)) + 240;
        for (int s2 = 0; s2 < 16; ++s2) {
            cur_s[t * 16 + s2] = run;
            run += ((cnt_s[t * 16 + s2] + GRP - 1) / GRP) * GRP;
        }
    }
    __syncthreads();
    for (int i = lo + t; i < hi; i += 1024) {
        const int li = (31 - __clz(i + 1)) - LEV0;
        const int pos = atomicAdd(&cur_s[li * 16 + x_sym[i]], 1);
        order[pos] = i;
    }
}

// -------- grouped level v2: 16 same-symbol nodes x 64 cols per block --------
// grid = ngroups*4 (4 column tiles). 256 threads = 4 waves; wave w = K-chunk
// [64w,64w+64). lane: ns=lane>>4 -> nodes ns*4..ns*4+3, g=lane&15 -> cols g*4.
// Cross-wave K reduce through part_s.
__global__ __launch_bounds__(256) void level_grouped(const int* __restrict__ x_sym,
                                                     const float* __restrict__ W,
                                                     const float* __restrict__ b,
                                                     float* __restrict__ enc,
                                                     const int* __restrict__ order,
                                                     int level_off, int leaf_children) {
    const int grp  = blockIdx.x >> 2;
    const int tile = blockIdx.x & 3;
    const int base = level_off + grp * GRP;
    const int n0 = order[base];
    if (n0 < 0) return;                 // block-uniform trailing padding
    const int s = x_sym[n0];
    const int t = threadIdx.x;
    const int w = t >> 6;
    const int lane = t & 63;

    __shared__ float  mean_s[GRP][MPAD];      // 16.6 KB
    __shared__ float4 part_s[4][4][64];       // 16 KB

    // ---- stage means: wave w stages nodes w*4+j over all 256 cols ----
    {
        const int c = lane << 2;
        #pragma unroll
        for (int j = 0; j < 4; ++j) {
            const int node = order[base + w * 4 + j];
            float4 m = make_float4(0.f, 0.f, 0.f, 0.f);
            if (node >= 0) {
                const int c0 = 2 * node + 1;
                if (leaf_children) {  // children are leaves: enc = tanh(b[sym])
                    const int sa = x_sym[c0], sb = x_sym[c0 + 1];
                    const float4 ba = *(const float4*)(b + sa * DIM + c);
                    const float4 bb = *(const float4*)(b + sb * DIM + c);
                    m.x = 0.5f * (tanhf(ba.x) + tanhf(bb.x));
                    m.y = 0.5f * (tanhf(ba.y) + tanhf(bb.y));
                    m.z = 0.5f * (tanhf(ba.z) + tanhf(bb.z));
                    m.w = 0.5f * (tanhf(ba.w) + tanhf(bb.w));
                } else {
                    const float4 ea = *(const float4*)(enc + (size_t)c0 * DIM + c);
                    const float4 eb = *(const float4*)(enc + (size_t)(c0 + 1) * DIM + c);
                    m.x = 0.5f * (ea.x + eb.x);
                    m.y = 0.5f * (ea.y + eb.y);
                    m.z = 0.5f * (ea.z + eb.z);
                    m.w = 0.5f * (ea.w + eb.w);
                }
            }
            *(float4*)(&mean_s[w * 4 + j][c]) = m;
        }
    }
    __syncthreads();

    // ---- compute ----
    const int ns4 = (lane >> 4) << 2;
    const int g4  = (lane & 15) << 2;
    const float* __restrict__ Ws =
        W + ((size_t)s << 16) + (size_t)(w * 64) * DIM + tile * 64 + g4;
    float4 acc0 = make_float4(0, 0, 0, 0), acc1 = acc0, acc2 = acc0, acc3 = acc0;
    const int dbase = w * 64;
    #pragma unroll 4
    for (int dd = 0; dd < 64; dd += 4) {
        const float4 w0 = *(const float4*)(Ws + (size_t)(dd + 0) * DIM);
        const float4 w1 = *(const float4*)(Ws + (size_t)(dd + 1) * DIM);
        const float4 w2 = *(const float4*)(Ws + (size_t)(dd + 2) * DIM);
        const float4 w3 = *(const float4*)(Ws + (size_t)(dd + 3) * DIM);
        const int d = dbase + dd;
        const float4 m0 = *(const float4*)(&mean_s[ns4 + 0][d]);
        const float4 m1 = *(const float4*)(&mean_s[ns4 + 1][d]);
        const float4 m2 = *(const float4*)(&mean_s[ns4 + 2][d]);
        const float4 m3 = *(const float4*)(&mean_s[ns4 + 3][d]);
        FMA4(acc0, m0.x, w0); FMA4(acc0, m0.y, w1); FMA4(acc0, m0.z, w2); FMA4(acc0, m0.w, w3);
        FMA4(acc1, m1.x, w0); FMA4(acc1, m1.y, w1); FMA4(acc1, m1.z, w2); FMA4(acc1, m1.w, w3);
        FMA4(acc2, m2.x, w0); FMA4(acc2, m2.y, w1); FMA4(acc2, m2.z, w2); FMA4(acc2, m2.w, w3);
        FMA4(acc3, m3.x, w0); FMA4(acc3, m3.y, w1); FMA4(acc3, m3.z, w2); FMA4(acc3, m3.w, w3);
    }
    part_s[w][0][lane] = acc0;
    part_s[w][1][lane] = acc1;
    part_s[w][2][lane] = acc2;
    part_s[w][3][lane] = acc3;
    __syncthreads();

    // ---- finalize: thread (w,lane) -> node ns4 + w, cols tile*64 + g4 ----
    const int node_l = ns4 + w;
    const int node_g = order[base + node_l];
    if (node_g >= 0) {
        float4 r        = part_s[0][w][lane];
        const float4 p1 = part_s[1][w][lane];
        const float4 p2 = part_s[2][w][lane];
        const float4 p3 = part_s[3][w][lane];
        const float4 bs = *(const float4*)(b + s * DIM + tile * 64 + g4);
        r.x = tanhf(r.x + p1.x + p2.x + p3.x + bs.x);
        r.y = tanhf(r.y + p1.y + p2.y + p3.y + bs.y);
        r.z = tanhf(r.z + p1.z + p2.z + p3.z + bs.z);
        r.w = tanhf(r.w + p1.w + p2.w + p3.w + bs.w);
        *(float4*)(enc + (size_t)node_g * DIM + tile * 64 + g4) = r;
    }
}

// -------- small levels (n <= 256): 4 blocks/node, 64-col tile + 4-way K split --------
__global__ __launch_bounds__(256) void level_small(const int* __restrict__ x_sym,
                                                   const float* __restrict__ W,
                                                   const float* __restrict__ b,
                                                   float* __restrict__ enc,
                                                   int lo, int N) {
    const int node = lo + (blockIdx.x >> 2);
    const int tile = blockIdx.x & 3;
    const int t = threadIdx.x;
    const int kc = t >> 6;
    const int lane = t & 63;
    const int c = tile * 64 + lane;

    __shared__ float mean_s[DIM];
    __shared__ float part[256];

    const int s = x_sym[node];
    const int c0 = 2 * node + 1;

    float m = 0.0f;
    if (c0 < N)
        m = 0.5f * (enc[(size_t)c0 * DIM + t] + enc[(size_t)(c0 + 1) * DIM + t]);
    mean_s[t] = m;
    __syncthreads();

    float acc = 0.0f;
    if (c0 < N) {
        const float* __restrict__ Ws = W + ((size_t)s << 16);
        const int d0 = kc * 64;
        #pragma unroll 8
        for (int d = d0; d < d0 + 64; ++d)
            acc = fmaf(mean_s[d], Ws[d * DIM + c], acc);
    }
    part[t] = acc;
    __syncthreads();

    if (t < 64) {
        float r = part[t] + part[t + 64] + part[t + 128] + part[t + 192];
        r += b[s * DIM + c];
        enc[(size_t)node * DIM + c] = tanhf(r);
    }
}

// legacy fallback (generic shapes)
__global__ __launch_bounds__(256) void level_big(const int* __restrict__ x_sym,
                                                 const float* __restrict__ W,
                                                 const float* __restrict__ b,
                                                 float* __restrict__ enc,
                                                 int lo, int N) {
    const int node = lo + blockIdx.x;
    const int e = threadIdx.x;
    __shared__ float mean_s[DIM];
    const int s = x_sym[node];
    const int c0 = 2 * node + 1;

    float acc = b[s * DIM + e];
    if (c0 < N) {
        mean_s[e] = 0.5f * (enc[(size_t)c0 * DIM + e] + enc[(size_t)(c0 + 1) * DIM + e]);
        __syncthreads();
        const float* __restrict__ Ws = W + ((size_t)s << 16);
        #pragma unroll 8
        for (int d = 0; d < DIM; ++d)
            acc = fmaf(mean_s[d], Ws[d * DIM + e], acc);
    }
    enc[(size_t)node * DIM + e] = tanhf(acc);
}

// -------- head: out = enc[root] @ W_out + b_out (OUT=10) --------
__global__ __launch_bounds__(256) void out_kernel10(const float* __restrict__ enc,
                                                    const float* __restrict__ W_out,
                                                    const float* __restrict__ b_out,
                                                    float* __restrict__ out) {
    const int t = threadIdx.x;
    const float e = enc[t];
    float p[10];
    #pragma unroll
    for (int o = 0; o < 10; ++o) p[o] = e * W_out[t * 10 + o];
    #pragma unroll
    for (int o = 0; o < 10; ++o)
        #pragma unroll
        for (int k = 32; k >= 1; k >>= 1) p[o] += __shfl_xor(p[o], k, 64);
    __shared__ float part[4][10];
    if ((t & 63) == 0) {
        #pragma unroll
        for (int o = 0; o < 10; ++o) part[t >> 6][o] = p[o];
    }
    __syncthreads();
    if (t < 10) out[t] = b_out[t] + part[0][t] + part[1][t] + part[2][t] + part[3][t];
}

__global__ void out_kernel(const float* __restrict__ enc,
                           const float* __restrict__ W_out,
                           const float* __restrict__ b_out,
                           float* __restrict__ out, int outn) {
    const int o = threadIdx.x;
    if (o < outn) {
        float acc = b_out[o];
        for (int d = 0; d < DIM; ++d)
            acc = fmaf(enc[d], W_out[d * outn + o], acc);
        out[o] = acc;
    }
}

extern "C" void kernel_launch(void* const* d_in, const int* in_sizes, int n_in,
                              void* d_out, int out_size, void* d_ws, size_t ws_size,
                              hipStream_t stream) {
    const int*   x_sym = (const int*)d_in[0];
    const float* W     = (const float*)d_in[2];
    const float* b     = (const float*)d_in[3];
    const float* W_out = (const float*)d_in[4];
    const float* b_out = (const float*)d_in[5];
    float* out = (float*)d_out;
    float* enc = (float*)d_ws;                      // N x 256 fp32
    const int N = in_sizes[0];

    int depth = 0;
    while (((1 << depth) - 1) < N) ++depth;

    if (N == (1 << 14) - 1 && out_size == 10) {
        int* order = (int*)(enc + (size_t)N * DIM);  // 8640 ints
        sort_kernel<<<1, 1024, 0, stream>>>(x_sym, order);
        // grouped deep levels, leaves folded into d = depth-2
        for (int d = LEV0 + NLEV - 1; d >= LEV0; --d) {
            const int li = d - LEV0;
            int off = 0;
            for (int k = 0; k < li; ++k) off += (1 << (LEV0 + k)) + 240;
            const int blocks = ((1 << d) / GRP + 15) * 4;   // groups x 4 col-tiles
            level_grouped<<<blocks, 256, 0, stream>>>(x_sym, W, b, enc, order, off,
                                                      (d == depth - 2) ? 1 : 0);
        }
        // small levels d = 8..0
        for (int d = LEV0 - 1; d >= 0; --d) {
            const int lo = (1 << d) - 1;
            const int n = (1 << d);
            level_small<<<n * 4, 256, 0, stream>>>(x_sym, W, b, enc, lo, N);
        }
        out_kernel10<<<1, 256, 0, stream>>>(enc, W_out, b_out, out);
    } else {
        for (int d = depth - 1; d >= 0; --d) {
            int lo = (1 << d) - 1;
            int n = (1 << d);
            if (lo + n > N) n = N - lo;
            if (n >= 256)
                level_big<<<n, 256, 0, stream>>>(x_sym, W, b, enc, lo, N);
            else
                level_small<<<n * 4, 256, 0, stream>>>(x_sym, W, b, enc, lo, N);
        }
        out_kernel<<<1, 64, 0, stream>>>(enc, W_out, b_out, out, out_size);
    }
}